// Round 1
// baseline (223.748 us; speedup 1.0000x reference)
//
#include <hip/hip_runtime.h>

// Problem constants
#define B   2
#define C   256
#define CM  64     // compressed channels
#define CE  100    // encoder out channels = K*K*S*S
#define H   40
#define W   40
#define HW  1600
#define KK  25     // K*K

// ---------------------------------------------------------------------------
// K1: 1x1 conv 256 -> 64.  grid (25 px-tiles, 2 b), block 256.
// Block handles 64 pixels x 64 oc. Wave = 16-oc group, lane = pixel.
// Weights are wave-uniform -> scalar loads.
// ---------------------------------------------------------------------------
__global__ __launch_bounds__(256) void k1_conv1x1(
    const float* __restrict__ x, const float* __restrict__ w,
    float* __restrict__ comp) {
  const int b = blockIdx.y;
  const int pbase = blockIdx.x * 64;
  __shared__ __align__(16) float xs[C * 64];   // 64 KB: [ic][px]

  // stage x[b, :, pbase..pbase+63] as float4
  const float4* x4 = (const float4*)(x + (size_t)b * C * HW + pbase);
  for (int i = threadIdx.x; i < C * 16; i += 256) {
    int ic = i >> 4, p4 = i & 15;
    ((float4*)xs)[ic * 16 + p4] = x4[ic * 400 + p4];   // ic*1600/4 = ic*400
  }
  __syncthreads();

  const int g = __builtin_amdgcn_readfirstlane(threadIdx.x >> 6); // wave id 0..3
  const int px = threadIdx.x & 63;
  float acc[16];
#pragma unroll
  for (int j = 0; j < 16; j++) acc[j] = 0.f;
  const float* wrow = w + (g * 16) * C;   // wave-uniform base
  for (int ic = 0; ic < C; ic++) {
    float xv = xs[ic * 64 + px];
#pragma unroll
    for (int j = 0; j < 16; j++) acc[j] += xv * wrow[j * C + ic]; // s_load
  }
  float* outp = comp + (size_t)b * CM * HW + pbase + px;
#pragma unroll
  for (int j = 0; j < 16; j++) outp[(g * 16 + j) * HW] = acc[j];
}

// ---------------------------------------------------------------------------
// K2: 3x3 conv 64 -> 100, pad 1.  grid (25 tiles, 4 oc-quarter, 2 b), block 256.
// Block: 8x8 spatial tile (lane = pixel), 25 oc split across 4 waves (7/7/7/4).
// Input tile (64ic x 10x10 halo) staged in LDS; weights wave-uniform -> s_load.
// ---------------------------------------------------------------------------
__global__ __launch_bounds__(256) void k2_conv3x3(
    const float* __restrict__ comp, const float* __restrict__ w,
    float* __restrict__ enc) {
  const int tile = blockIdx.x;
  const int ty = tile / 5, tx = tile % 5;
  const int ocq = blockIdx.y;
  const int b = blockIdx.z;
  __shared__ float cs[CM * 100];   // 25.6 KB: [ic][yy*10+xx]

  const float* cb = comp + (size_t)b * CM * HW;
  for (int i = threadIdx.x; i < CM * 100; i += 256) {
    int ic = i / 100, r = i % 100;
    int yy = r / 10, xx = r % 10;
    int gy = ty * 8 + yy - 1, gx = tx * 8 + xx - 1;
    float v = 0.f;
    if (gy >= 0 && gy < H && gx >= 0 && gx < W) v = cb[ic * HW + gy * W + gx];
    cs[i] = v;
  }
  __syncthreads();

  const int wv = __builtin_amdgcn_readfirstlane(threadIdx.x >> 6);
  const int lane = threadIdx.x & 63;
  const int py = lane >> 3, px = lane & 7;
  const int ocs = ocq * 25 + wv * 7;           // wave-uniform
  const int nj = (wv == 3) ? 4 : 7;
  float acc[7];
#pragma unroll
  for (int j = 0; j < 7; j++) acc[j] = 0.f;
  const float* wb = w + (size_t)ocs * 576;     // [oc][ic][dy][dx]
  for (int ic = 0; ic < CM; ic++) {
#pragma unroll
    for (int dy = 0; dy < 3; dy++) {
#pragma unroll
      for (int dx = 0; dx < 3; dx++) {
        float xv = cs[ic * 100 + (py + dy) * 10 + (px + dx)];
        const float* wp = wb + ic * 9 + dy * 3 + dx;
#pragma unroll
        for (int j = 0; j < 7; j++)
          if (j < nj) acc[j] += xv * wp[j * 576];   // s_load (uniform)
      }
    }
  }
  float* ob = enc + (size_t)b * CE * HW + (ty * 8 + py) * W + (tx * 8 + px);
  for (int j = 0; j < nj; j++) ob[(ocs + j) * HW] = acc[j];
}

// ---------------------------------------------------------------------------
// K3: softmax over 25 + reassembly.
// grid (80 = i0*2+jhalf, 4 c-quarter, 2 b), block 256 (4 waves).
// Output flat spatial index within a (b,c) plane: f = p*4+d, p = i0*40+j0.
// Block covers source row i0, j0 in [jh*20, jh*20+20), 64 channels.
// Phase 1 (80 threads): softmax weights -> LDS [j0loc][k][d] (float4-readable).
// Phase 2: lane = channel, wave-uniform j0; 25 taps from LDS x tile
//          (stride 121 -> conflict-free), float4 weight broadcast, float4 store.
// ---------------------------------------------------------------------------
__global__ __launch_bounds__(256) void k3_reassemble(
    const float* __restrict__ x, const float* __restrict__ enc,
    float* __restrict__ out) {
  const int i0 = blockIdx.x >> 1;
  const int jh = blockIdx.x & 1;       // j0 half: [jh*20, jh*20+20)
  const int cq = blockIdx.y;
  const int b = blockIdx.z;

  __shared__ __align__(16) float wlds[20 * KK * 4];  // 8 KB  [j0loc][k][d]
  __shared__ float xsm[64 * 121];                    // 31 KB [c][r*24 + t]

  const int tid = threadIdx.x;

  // ---- phase 1: softmax weights for 80 output elems (20 j0 x 4 d)
  if (tid < 80) {
    const int e = jh * 80 + tid;       // global elem in row-block [0,160)
    const int j0 = e >> 2, d = e & 3;
    const int off = ((e >= 80) ? 2 : 0) + (e & 1);
    const int col = ((e >= 80) ? (j0 - 20) : j0) * 2 + (d >> 1);
    const float* ep = enc + (size_t)b * CE * HW + i0 * W + col;
    float v[KK];
    float m = -1e30f;
#pragma unroll
    for (int k = 0; k < KK; k++) {
      v[k] = ep[(k * 4 + off) * HW];
      m = fmaxf(m, v[k]);
    }
    float s = 0.f;
#pragma unroll
    for (int k = 0; k < KK; k++) {
      v[k] = expf(v[k] - m);
      s += v[k];
    }
    const float inv = 1.f / s;
    const int j0l = j0 - jh * 20;
#pragma unroll
    for (int k = 0; k < KK; k++) wlds[(j0l * KK + k) * 4 + d] = v[k] * inv;
  }

  // ---- stage x tile: 64 c x 5 rows x 24 cols (zero-padded halo)
  const float* xb = x + ((size_t)b * C + cq * 64) * HW;
  for (int i = tid; i < 64 * 120; i += 256) {
    int c = i / 120;
    int rr = i % 120;
    int r = rr / 24, t = rr % 24;
    int gy = i0 - 2 + r;
    int gx = jh * 20 + t - 2;
    float v = 0.f;
    if (gy >= 0 && gy < H && gx >= 0 && gx < W) v = xb[c * HW + gy * W + gx];
    xsm[c * 121 + r * 24 + t] = v;
  }
  __syncthreads();

  // ---- phase 2
  const int wv = tid >> 6;
  const int lane = tid & 63;
  float* ob = out + (((size_t)b * C + cq * 64 + lane) * 6400) + i0 * 160;
  const float* xrow = &xsm[lane * 121];
#pragma unroll 1
  for (int jj = 0; jj < 5; jj++) {
    const int j0l = wv * 5 + jj;              // local j0 in [0,20)
    const int j0 = jh * 20 + j0l;             // global j0
    float a0 = 0.f, a1 = 0.f, a2 = 0.f, a3 = 0.f;
#pragma unroll
    for (int ki = 0; ki < 5; ki++) {
#pragma unroll
      for (int kj = 0; kj < 5; kj++) {
        float xv = xrow[ki * 24 + j0l + kj];
        float4 w4 = *(const float4*)&wlds[(j0l * KK + ki * 5 + kj) * 4];
        a0 += xv * w4.x;
        a1 += xv * w4.y;
        a2 += xv * w4.z;
        a3 += xv * w4.w;
      }
    }
    float4 o = make_float4(a0, a1, a2, a3);
    *(float4*)&ob[j0 * 4] = o;
  }
}

// ---------------------------------------------------------------------------
extern "C" void kernel_launch(void* const* d_in, const int* in_sizes, int n_in,
                              void* d_out, int out_size, void* d_ws, size_t ws_size,
                              hipStream_t stream) {
  const float* x      = (const float*)d_in[0];
  const float* w_comp = (const float*)d_in[1];
  const float* w_enc  = (const float*)d_in[2];
  float* out = (float*)d_out;

  float* comp = (float*)d_ws;                         // B*CM*HW*4 = 819200 B
  float* enc  = (float*)((char*)d_ws + (size_t)B * CM * HW * sizeof(float));

  k1_conv1x1<<<dim3(25, B), 256, 0, stream>>>(x, w_comp, comp);
  k2_conv3x3<<<dim3(25, 4, B), 256, 0, stream>>>(comp, w_enc, enc);
  k3_reassemble<<<dim3(80, 4, B), 256, 0, stream>>>(x, enc, out);
}

// Round 2
// 112.660 us; speedup vs baseline: 1.9860x; 1.9860x over previous
//
#include <hip/hip_runtime.h>

#define B   2
#define C   256
#define CM  64     // compressed channels
#define CE  100    // encoder out channels
#define H   40
#define W   40
#define HW  1600
#define KK  25     // K*K

static __device__ __forceinline__ unsigned short f2bf(float f) {
  union { float f; unsigned u; } v; v.f = f;
  unsigned r = v.u + 0x7FFFu + ((v.u >> 16) & 1u);   // RNE
  return (unsigned short)(r >> 16);
}
static __device__ __forceinline__ float bf2f(unsigned short s) {
  union { float f; unsigned u; } v; v.u = ((unsigned)s) << 16;
  return v.f;
}

// ---------------------------------------------------------------------------
// K1: 1x1 conv 256 -> 64 as LDS GEMM, ic split in half across blocks.
// grid (25 px-tiles, 2 ic-halves, 2 b), block 256 = 16 ty(oc) x 16 tx(px),
// each thread 4 oc x 4 px. Output: bf16 partial sums pc[ich][b][64][1600].
// ---------------------------------------------------------------------------
__global__ __launch_bounds__(256) void k1_conv1x1(
    const float* __restrict__ x, const float* __restrict__ w,
    unsigned short* __restrict__ pc) {
  const int t = blockIdx.x, ich = blockIdx.y, b = blockIdx.z;
  __shared__ __align__(16) float xs[128 * 64];    // 32 KB [icl][px]
  __shared__ __align__(16) float wsA[128 * 64];   // 32 KB [icl][oc] (transposed)
  const int tid = threadIdx.x;

  // stage x tile (coalesced float4)
  const float4* x4 = (const float4*)(x + ((size_t)b * C + ich * 128) * HW + t * 64);
#pragma unroll
  for (int i = 0; i < 8; i++) {
    int idx = tid + i * 256;                       // icl = idx>>4, q = idx&15
    ((float4*)xs)[idx] = x4[(idx >> 4) * 400 + (idx & 15)];
  }
  // stage weights transposed: read w[oc][ic] float4 along ic (scattered 16B,
  // L2-resident), write LDS conflict-free (consecutive lanes -> consecutive oc)
  const float4* w4 = (const float4*)w;             // w viewed [64][64] float4
#pragma unroll
  for (int i = 0; i < 8; i++) {
    int idx = tid + i * 256;
    int icq = idx >> 6, oc = idx & 63;
    float4 f = w4[oc * 64 + ich * 32 + icq];
    wsA[(icq * 4 + 0) * 64 + oc] = f.x;
    wsA[(icq * 4 + 1) * 64 + oc] = f.y;
    wsA[(icq * 4 + 2) * 64 + oc] = f.z;
    wsA[(icq * 4 + 3) * 64 + oc] = f.w;
  }
  __syncthreads();

  const int ty = tid >> 4, tx = tid & 15;
  float acc[4][4];
#pragma unroll
  for (int i = 0; i < 4; i++)
#pragma unroll
    for (int j = 0; j < 4; j++) acc[i][j] = 0.f;

#pragma unroll 4
  for (int icl = 0; icl < 128; icl++) {
    float4 a = *(const float4*)&wsA[icl * 64 + ty * 4];
    float4 bb = *(const float4*)&xs[icl * 64 + tx * 4];
    float av[4] = {a.x, a.y, a.z, a.w};
    float bv[4] = {bb.x, bb.y, bb.z, bb.w};
#pragma unroll
    for (int i = 0; i < 4; i++)
#pragma unroll
      for (int j = 0; j < 4; j++) acc[i][j] += av[i] * bv[j];
  }

  unsigned short* o = pc + (((size_t)ich * B + b) * CM) * HW + t * 64 + tx * 4;
#pragma unroll
  for (int j = 0; j < 4; j++) {
    ushort4 u;
    u.x = f2bf(acc[j][0]); u.y = f2bf(acc[j][1]);
    u.z = f2bf(acc[j][2]); u.w = f2bf(acc[j][3]);
    *(ushort4*)&o[(size_t)(ty * 4 + j) * HW] = u;
  }
}

// ---------------------------------------------------------------------------
// K2: 3x3 conv 64 -> 100. grid (25 tiles, 4 ocq, 2 b), block 256.
// Lane = pixel of 8x8 tile; the 4 waves k-split the 64 ic (16 each), all
// 25 oc per wave via float4 LDS *broadcasts*. Weights staged [k][28-pad] in
// two k-chunks; the partial-accumulator aliases the weight buffer (barriered).
// LDS: 25.6 (cs) + 32.25 (wsC) = 57.9 KB.
// ---------------------------------------------------------------------------
__global__ __launch_bounds__(256) void k2_conv3x3(
    const unsigned short* __restrict__ pc, const float* __restrict__ w,
    float* __restrict__ enc) {
  const int tile = blockIdx.x, ocq = blockIdx.y, b = blockIdx.z;
  const int ty5 = tile / 5, tx5 = tile % 5;
  __shared__ __align__(16) float cs[CM * 100];       // comp halo [ic][10x10]
  __shared__ __align__(16) float wsC[4 * 72 * 28];   // per-wave k-chunk slices
  float* pacc = wsC;                                 // alias after final chunk
  const int tid = threadIdx.x;

  // ---- cs staging: sum the two bf16 ic-half partials
  const unsigned short* p0 = pc + (size_t)b * CM * HW;
  const unsigned short* p1 = pc + (size_t)(B + b) * CM * HW;
  for (int i = tid; i < CM * 100; i += 256) {
    int ic = i / 100, r = i - ic * 100;
    int yy = r / 10, xx = r - yy * 10;
    int gy = ty5 * 8 + yy - 1, gx = tx5 * 8 + xx - 1;
    float v = 0.f;
    if (gy >= 0 && gy < H && gx >= 0 && gx < W) {
      int idx = ic * HW + gy * W + gx;
      v = bf2f(p0[idx]) + bf2f(p1[idx]);
    }
    cs[i] = v;
  }

  const int wv = tid >> 6, lane = tid & 63, py = lane >> 3, px = lane & 7;
  float acc[KK];
#pragma unroll
  for (int j = 0; j < KK; j++) acc[j] = 0.f;

  const float4* w4 = (const float4*)(w + (size_t)ocq * 25 * 576);
  for (int c = 0; c < 2; c++) {
    if (c) __syncthreads();      // previous chunk's k-loop done before overwrite
    // stage wsC: rows klo in [0,72) per wave slice; global k = wv*144+c*72+klo
    for (int i = tid; i < 1800; i += 256) {
      int ol = i % 25;
      int rr = i / 25;                       // 0..71
      int wvs = rr / 18, kq = rr - wvs * 18; // kq in [0,18)
      float4 f = w4[ol * 144 + wvs * 36 + c * 18 + kq];
      float* dst = &wsC[wvs * 2016 + ol];
      int k0 = kq * 4;
      dst[(k0 + 0) * 28] = f.x;
      dst[(k0 + 1) * 28] = f.y;
      dst[(k0 + 2) * 28] = f.z;
      dst[(k0 + 3) * 28] = f.w;
    }
    __syncthreads();

    const float* wslice = &wsC[wv * 2016];
#pragma unroll 1
    for (int icl = 0; icl < 8; icl++) {
      const int ic = wv * 16 + c * 8 + icl;
      const float* csr = &cs[ic * 100 + py * 10 + px];
#pragma unroll
      for (int dy = 0; dy < 3; dy++) {
#pragma unroll
        for (int dx = 0; dx < 3; dx++) {
          float xv = csr[dy * 10 + dx];
          const float4* wr = (const float4*)&wslice[(icl * 9 + dy * 3 + dx) * 28];
          float4 w0 = wr[0], w1 = wr[1], w2 = wr[2], w3 = wr[3];
          float4 w4v = wr[4], w5 = wr[5];
          float w6 = wslice[(icl * 9 + dy * 3 + dx) * 28 + 24];
          acc[0]  += xv * w0.x;  acc[1]  += xv * w0.y;  acc[2]  += xv * w0.z;  acc[3]  += xv * w0.w;
          acc[4]  += xv * w1.x;  acc[5]  += xv * w1.y;  acc[6]  += xv * w1.z;  acc[7]  += xv * w1.w;
          acc[8]  += xv * w2.x;  acc[9]  += xv * w2.y;  acc[10] += xv * w2.z;  acc[11] += xv * w2.w;
          acc[12] += xv * w3.x;  acc[13] += xv * w3.y;  acc[14] += xv * w3.z;  acc[15] += xv * w3.w;
          acc[16] += xv * w4v.x; acc[17] += xv * w4v.y; acc[18] += xv * w4v.z; acc[19] += xv * w4v.w;
          acc[20] += xv * w5.x;  acc[21] += xv * w5.y;  acc[22] += xv * w5.z;  acc[23] += xv * w5.w;
          acc[24] += xv * w6;
        }
      }
    }
  }
  __syncthreads();               // all waves done reading wsC -> alias as pacc
#pragma unroll
  for (int j = 0; j < KK; j++) pacc[(wv * KK + j) * 64 + lane] = acc[j];
  __syncthreads();

  float* eb = enc + ((size_t)b * CE + ocq * 25) * HW;
  for (int i = tid; i < 1600; i += 256) {
    int ol = i >> 6, p = i & 63;
    float s = pacc[ol * 64 + p] + pacc[(KK + ol) * 64 + p] +
              pacc[(2 * KK + ol) * 64 + p] + pacc[(3 * KK + ol) * 64 + p];
    int gy = ty5 * 8 + (p >> 3), gx = tx5 * 8 + (p & 7);
    eb[ol * HW + gy * W + gx] = s;
  }
}

// ---------------------------------------------------------------------------
// K3: softmax over 25 + reassembly (unchanged from round 1 — verified).
// ---------------------------------------------------------------------------
__global__ __launch_bounds__(256) void k3_reassemble(
    const float* __restrict__ x, const float* __restrict__ enc,
    float* __restrict__ out) {
  const int i0 = blockIdx.x >> 1;
  const int jh = blockIdx.x & 1;
  const int cq = blockIdx.y;
  const int b = blockIdx.z;

  __shared__ __align__(16) float wlds[20 * KK * 4];  // 8 KB  [j0loc][k][d]
  __shared__ float xsm[64 * 121];                    // 31 KB [c][r*24 + t]

  const int tid = threadIdx.x;

  if (tid < 80) {
    const int e = jh * 80 + tid;
    const int j0 = e >> 2, d = e & 3;
    const int off = ((e >= 80) ? 2 : 0) + (e & 1);
    const int col = ((e >= 80) ? (j0 - 20) : j0) * 2 + (d >> 1);
    const float* ep = enc + (size_t)b * CE * HW + i0 * W + col;
    float v[KK];
    float m = -1e30f;
#pragma unroll
    for (int k = 0; k < KK; k++) {
      v[k] = ep[(k * 4 + off) * HW];
      m = fmaxf(m, v[k]);
    }
    float s = 0.f;
#pragma unroll
    for (int k = 0; k < KK; k++) {
      v[k] = expf(v[k] - m);
      s += v[k];
    }
    const float inv = 1.f / s;
    const int j0l = j0 - jh * 20;
#pragma unroll
    for (int k = 0; k < KK; k++) wlds[(j0l * KK + k) * 4 + d] = v[k] * inv;
  }

  const float* xb = x + ((size_t)b * C + cq * 64) * HW;
  for (int i = tid; i < 64 * 120; i += 256) {
    int c = i / 120;
    int rr = i % 120;
    int r = rr / 24, t = rr % 24;
    int gy = i0 - 2 + r;
    int gx = jh * 20 + t - 2;
    float v = 0.f;
    if (gy >= 0 && gy < H && gx >= 0 && gx < W) v = xb[c * HW + gy * W + gx];
    xsm[c * 121 + r * 24 + t] = v;
  }
  __syncthreads();

  const int wv = tid >> 6;
  const int lane = tid & 63;
  float* ob = out + (((size_t)b * C + cq * 64 + lane) * 6400) + i0 * 160;
  const float* xrow = &xsm[lane * 121];
#pragma unroll 1
  for (int jj = 0; jj < 5; jj++) {
    const int j0l = wv * 5 + jj;
    const int j0 = jh * 20 + j0l;
    float a0 = 0.f, a1 = 0.f, a2 = 0.f, a3 = 0.f;
#pragma unroll
    for (int ki = 0; ki < 5; ki++) {
#pragma unroll
      for (int kj = 0; kj < 5; kj++) {
        float xv = xrow[ki * 24 + j0l + kj];
        float4 w4 = *(const float4*)&wlds[(j0l * KK + ki * 5 + kj) * 4];
        a0 += xv * w4.x;
        a1 += xv * w4.y;
        a2 += xv * w4.z;
        a3 += xv * w4.w;
      }
    }
    float4 o = make_float4(a0, a1, a2, a3);
    *(float4*)&ob[j0 * 4] = o;
  }
}

// ---------------------------------------------------------------------------
extern "C" void kernel_launch(void* const* d_in, const int* in_sizes, int n_in,
                              void* d_out, int out_size, void* d_ws, size_t ws_size,
                              hipStream_t stream) {
  const float* x      = (const float*)d_in[0];
  const float* w_comp = (const float*)d_in[1];
  const float* w_enc  = (const float*)d_in[2];
  float* out = (float*)d_out;

  unsigned short* pc = (unsigned short*)d_ws;        // 2*2*64*1600*2 = 819200 B
  float* enc = (float*)((char*)d_ws + 819200);       // 2*100*1600*4 = 1280000 B

  k1_conv1x1<<<dim3(25, 2, B), 256, 0, stream>>>(x, w_comp, pc);
  k2_conv3x3<<<dim3(25, 4, B), 256, 0, stream>>>(pc, w_enc, enc);
  k3_reassemble<<<dim3(80, 4, B), 256, 0, stream>>>(x, enc, out);
}

// Round 3
// 110.271 us; speedup vs baseline: 2.0291x; 1.0217x over previous
//
#include <hip/hip_runtime.h>

#define B   2
#define C   256
#define CM  64     // compressed channels
#define CE  100    // encoder out channels
#define H   40
#define W   40
#define HW  1600
#define KK  25     // K*K

// ---------------------------------------------------------------------------
// K1: 1x1 conv 256 -> 64 as LDS GEMM, K(=x channels) split 4-way over blocks.
// grid (25 px-tiles, 4 K-quarters, 2 b), block 256 = 16 ty(oc) x 16 tx(px),
// thread tile 4 oc x 4 px. Output: fp32 partials pc[ich][b][64][1600].
// ---------------------------------------------------------------------------
__global__ __launch_bounds__(256) void k1_conv1x1(
    const float* __restrict__ x, const float* __restrict__ w,
    float* __restrict__ pc) {
  const int t = blockIdx.x, ich = blockIdx.y, b = blockIdx.z;
  __shared__ __align__(16) float xs[64 * 64];    // 16 KB [icl][px]
  __shared__ __align__(16) float wsA[64 * 64];   // 16 KB [icl][oc] (transposed)
  const int tid = threadIdx.x;

  // stage x tile (coalesced float4): 64 icl x 64 px
  const float4* x4 = (const float4*)(x + ((size_t)b * C + ich * 64) * HW + t * 64);
#pragma unroll
  for (int i = 0; i < 4; i++) {
    int idx = tid + i * 256;                     // icl = idx>>4, q = idx&15
    ((float4*)xs)[idx] = x4[(idx >> 4) * 400 + (idx & 15)];
  }
  // stage weights transposed (w viewed [64 oc][64 f4-of-ic])
  const float4* w4 = (const float4*)w;
#pragma unroll
  for (int i = 0; i < 4; i++) {
    int idx = tid + i * 256;
    int icq = idx >> 6, oc = idx & 63;           // icq 0..15
    float4 f = w4[oc * 64 + ich * 16 + icq];
    wsA[(icq * 4 + 0) * 64 + oc] = f.x;
    wsA[(icq * 4 + 1) * 64 + oc] = f.y;
    wsA[(icq * 4 + 2) * 64 + oc] = f.z;
    wsA[(icq * 4 + 3) * 64 + oc] = f.w;
  }
  __syncthreads();

  const int ty = tid >> 4, tx = tid & 15;
  float acc[4][4];
#pragma unroll
  for (int i = 0; i < 4; i++)
#pragma unroll
    for (int j = 0; j < 4; j++) acc[i][j] = 0.f;

#pragma unroll 4
  for (int icl = 0; icl < 64; icl++) {
    float4 a = *(const float4*)&wsA[icl * 64 + ty * 4];
    float4 bb = *(const float4*)&xs[icl * 64 + tx * 4];
    float av[4] = {a.x, a.y, a.z, a.w};
    float bv[4] = {bb.x, bb.y, bb.z, bb.w};
#pragma unroll
    for (int i = 0; i < 4; i++)
#pragma unroll
      for (int j = 0; j < 4; j++) acc[i][j] += av[i] * bv[j];
  }

  float* o = pc + ((size_t)ich * B + b) * CM * HW + t * 64 + tx * 4;
#pragma unroll
  for (int j = 0; j < 4; j++)
    *(float4*)&o[(size_t)(ty * 4 + j) * HW] =
        make_float4(acc[j][0], acc[j][1], acc[j][2], acc[j][3]);
}

// ---------------------------------------------------------------------------
// K2: 3x3 conv 64 -> 100, pad 1.  grid (25 tiles, 4 ocq, 4 icq) = 400 blocks;
// both batch images merged into the block (lane = px of 8x8 tile, 2 acc sets).
// 4 waves k-split the block's 16 ic (4 each); 25 oc via float4 LDS broadcasts
// (each broadcast feeds 50 FMAs). Cross-wave tree-reduce through aliased LDS.
// Writes fp32 partials encP[icq][b][100][1600], summed in k3 phase 1.
// ---------------------------------------------------------------------------
__global__ __launch_bounds__(256) void k2_conv3x3(
    const float* __restrict__ pc, const float* __restrict__ w,
    float* __restrict__ encP) {
  const int tile = blockIdx.x, ocq = blockIdx.y, icq = blockIdx.z;
  const int ty5 = tile / 5, tx5 = tile % 5;
  __shared__ __align__(16) float smem[3200 + 16 * 9 * 28];  // 28.9 KB
  float* cs  = smem;          // [bb2][icl16][10x10 halo]
  float* wsb = smem + 3200;   // [icl16][tap9][oc pad 28]
  float* pacc = smem;         // alias for reduction (needs 6400 <= 7232)
  const int tid = threadIdx.x;

  // ---- stage cs: comp halo = sum of 4 fp32 K-partials (pc strides: ich 204800, b 102400)
  for (int i = tid; i < 3200; i += 256) {
    int bb = i / 1600, r = i - bb * 1600;
    int icl = r / 100, rr = r - icl * 100;
    int yy = rr / 10, xx = rr - yy * 10;
    int gy = ty5 * 8 + yy - 1, gx = tx5 * 8 + xx - 1;
    float v = 0.f;
    if (gy >= 0 && gy < H && gx >= 0 && gx < W) {
      int o = bb * 102400 + (icq * 16 + icl) * HW + gy * W + gx;
      v = pc[o] + pc[204800 + o] + pc[409600 + o] + pc[614400 + o];
    }
    cs[i] = v;
  }
  // ---- stage weights: ws[(icl*9+tap)*28 + ol] = w[(ocq*25+ol)*576 + (icq*16+icl)*9 + tap]
  const float* wb = w + (size_t)(ocq * 25) * 576 + (size_t)(icq * 16) * 9;
  for (int i = tid; i < 3600; i += 256) {
    int ol = i / 144, r = i - ol * 144;
    wsb[r * 28 + ol] = wb[ol * 576 + r];
  }
  __syncthreads();

  const int wv = tid >> 6, lane = tid & 63, py = lane >> 3, px = lane & 7;
  float acc[50];
#pragma unroll
  for (int j = 0; j < 50; j++) acc[j] = 0.f;

#pragma unroll 1
  for (int t = 0; t < 4; t++) {
    const int icl = wv * 4 + t;
    const float* c0 = &cs[icl * 100 + py * 10 + px];
    const float* c1 = c0 + 1600;
    const float* wrow = &wsb[icl * 9 * 28];
#pragma unroll
    for (int dy = 0; dy < 3; dy++) {
#pragma unroll
      for (int dx = 0; dx < 3; dx++) {
        float x0 = c0[dy * 10 + dx];
        float x1 = c1[dy * 10 + dx];
        const float* wp = &wrow[(dy * 3 + dx) * 28];
        float4 w0 = *(const float4*)&wp[0],  w1 = *(const float4*)&wp[4];
        float4 w2 = *(const float4*)&wp[8],  w3 = *(const float4*)&wp[12];
        float4 w4v = *(const float4*)&wp[16], w5 = *(const float4*)&wp[20];
        float w6 = wp[24];
        acc[0]  += x0 * w0.x;  acc[1]  += x0 * w0.y;  acc[2]  += x0 * w0.z;  acc[3]  += x0 * w0.w;
        acc[4]  += x0 * w1.x;  acc[5]  += x0 * w1.y;  acc[6]  += x0 * w1.z;  acc[7]  += x0 * w1.w;
        acc[8]  += x0 * w2.x;  acc[9]  += x0 * w2.y;  acc[10] += x0 * w2.z;  acc[11] += x0 * w2.w;
        acc[12] += x0 * w3.x;  acc[13] += x0 * w3.y;  acc[14] += x0 * w3.z;  acc[15] += x0 * w3.w;
        acc[16] += x0 * w4v.x; acc[17] += x0 * w4v.y; acc[18] += x0 * w4v.z; acc[19] += x0 * w4v.w;
        acc[20] += x0 * w5.x;  acc[21] += x0 * w5.y;  acc[22] += x0 * w5.z;  acc[23] += x0 * w5.w;
        acc[24] += x0 * w6;
        acc[25] += x1 * w0.x;  acc[26] += x1 * w0.y;  acc[27] += x1 * w0.z;  acc[28] += x1 * w0.w;
        acc[29] += x1 * w1.x;  acc[30] += x1 * w1.y;  acc[31] += x1 * w1.z;  acc[32] += x1 * w1.w;
        acc[33] += x1 * w2.x;  acc[34] += x1 * w2.y;  acc[35] += x1 * w2.z;  acc[36] += x1 * w2.w;
        acc[37] += x1 * w3.x;  acc[38] += x1 * w3.y;  acc[39] += x1 * w3.z;  acc[40] += x1 * w3.w;
        acc[41] += x1 * w4v.x; acc[42] += x1 * w4v.y; acc[43] += x1 * w4v.z; acc[44] += x1 * w4v.w;
        acc[45] += x1 * w5.x;  acc[46] += x1 * w5.y;  acc[47] += x1 * w5.z;  acc[48] += x1 * w5.w;
        acc[49] += x1 * w6;
      }
    }
  }

  // ---- cross-wave reduction (waves hold different ic slices)
  __syncthreads();                       // everyone done reading cs/wsb
  if (wv == 1 || wv == 3) {
    const int slot = wv >> 1;
#pragma unroll
    for (int j = 0; j < 50; j++) pacc[slot * 3200 + j * 64 + lane] = acc[j];
  }
  __syncthreads();
  if (wv == 0 || wv == 2) {
    const int slot = wv >> 1;
#pragma unroll
    for (int j = 0; j < 50; j++) acc[j] += pacc[slot * 3200 + j * 64 + lane];
  }
  __syncthreads();
  if (wv == 2) {
#pragma unroll
    for (int j = 0; j < 50; j++) pacc[j * 64 + lane] = acc[j];
  }
  __syncthreads();
  if (wv == 0) {
    const int base_px = (ty5 * 8 + py) * W + tx5 * 8 + px;
#pragma unroll
    for (int bb = 0; bb < 2; bb++)
#pragma unroll
      for (int ol = 0; ol < 25; ol++)
        encP[(((size_t)icq * 2 + bb) * CE + ocq * 25 + ol) * HW + base_px] =
            acc[bb * 25 + ol] + pacc[(bb * 25 + ol) * 64 + lane];
  }
}

// ---------------------------------------------------------------------------
// K3: softmax over 25 (summing 4 enc partials) + reassembly.
// grid (80 = i0*2+jhalf, 4 cq, 2 b), block 256.
// ---------------------------------------------------------------------------
__global__ __launch_bounds__(256) void k3_reassemble(
    const float* __restrict__ x, const float* __restrict__ encP,
    float* __restrict__ out) {
  const int i0 = blockIdx.x >> 1;
  const int jh = blockIdx.x & 1;
  const int cq = blockIdx.y;
  const int b = blockIdx.z;

  __shared__ __align__(16) float wlds[20 * KK * 4];  // 8 KB  [j0loc][k][d]
  __shared__ float xsm[64 * 121];                    // 31 KB [c][r*24 + t]

  const int tid = threadIdx.x;

  if (tid < 80) {
    const int e = jh * 80 + tid;
    const int j0 = e >> 2, d = e & 3;
    const int off = ((e >= 80) ? 2 : 0) + (e & 1);
    const int col = ((e >= 80) ? (j0 - 20) : j0) * 2 + (d >> 1);
    const float* ep = encP + (size_t)b * CE * HW + i0 * W + col;
    float v[KK];
    float m = -1e30f;
#pragma unroll
    for (int k = 0; k < KK; k++) {
      int o = (k * 4 + off) * HW;
      v[k] = ep[o] + ep[320000 + o] + ep[640000 + o] + ep[960000 + o];
      m = fmaxf(m, v[k]);
    }
    float s = 0.f;
#pragma unroll
    for (int k = 0; k < KK; k++) {
      v[k] = expf(v[k] - m);
      s += v[k];
    }
    const float inv = 1.f / s;
    const int j0l = j0 - jh * 20;
#pragma unroll
    for (int k = 0; k < KK; k++) wlds[(j0l * KK + k) * 4 + d] = v[k] * inv;
  }

  const float* xb = x + ((size_t)b * C + cq * 64) * HW;
  for (int i = tid; i < 64 * 120; i += 256) {
    int c = i / 120;
    int rr = i % 120;
    int r = rr / 24, t = rr % 24;
    int gy = i0 - 2 + r;
    int gx = jh * 20 + t - 2;
    float v = 0.f;
    if (gy >= 0 && gy < H && gx >= 0 && gx < W) v = xb[c * HW + gy * W + gx];
    xsm[c * 121 + r * 24 + t] = v;
  }
  __syncthreads();

  const int wv = tid >> 6;
  const int lane = tid & 63;
  float* ob = out + (((size_t)b * C + cq * 64 + lane) * 6400) + i0 * 160;
  const float* xrow = &xsm[lane * 121];
#pragma unroll 1
  for (int jj = 0; jj < 5; jj++) {
    const int j0l = wv * 5 + jj;
    const int j0 = jh * 20 + j0l;
    float a0 = 0.f, a1 = 0.f, a2 = 0.f, a3 = 0.f;
#pragma unroll
    for (int ki = 0; ki < 5; ki++) {
#pragma unroll
      for (int kj = 0; kj < 5; kj++) {
        float xv = xrow[ki * 24 + j0l + kj];
        float4 w4 = *(const float4*)&wlds[(j0l * KK + ki * 5 + kj) * 4];
        a0 += xv * w4.x;
        a1 += xv * w4.y;
        a2 += xv * w4.z;
        a3 += xv * w4.w;
      }
    }
    float4 o = make_float4(a0, a1, a2, a3);
    *(float4*)&ob[j0 * 4] = o;
  }
}

// ---------------------------------------------------------------------------
extern "C" void kernel_launch(void* const* d_in, const int* in_sizes, int n_in,
                              void* d_out, int out_size, void* d_ws, size_t ws_size,
                              hipStream_t stream) {
  const float* x      = (const float*)d_in[0];
  const float* w_comp = (const float*)d_in[1];
  const float* w_enc  = (const float*)d_in[2];
  float* out = (float*)d_out;

  float* pc   = (float*)d_ws;                        // 4*2*64*1600*4  = 3,276,800 B
  float* encP = (float*)((char*)d_ws + 3276800);     // 4*2*100*1600*4 = 5,120,000 B

  k1_conv1x1<<<dim3(25, 4, B), 256, 0, stream>>>(x, w_comp, pc);
  k2_conv3x3<<<dim3(25, 4, 4), 256, 0, stream>>>(pc, w_enc, encP);
  k3_reassemble<<<dim3(80, 4, B), 256, 0, stream>>>(x, encP, out);
}